// Round 8
// baseline (178.780 us; speedup 1.0000x reference)
//
#include <hip/hip_runtime.h>
#include <hip/hip_bf16.h>

#define BATCH 2048
#define DIM   100000
#define STEPS 3125              // DIM / 32 (exact)
#define NSPLIT 32               // 21 splits of 98 steps + 11 of 97 (=3125)
#define NTILES 25               // 24 full 4-step tiles + tail (2 or 1 steps)
#define ROWTILES 128            // 2048 / 16

typedef float f32x4  __attribute__((ext_vector_type(4)));
typedef short bf16x8 __attribute__((ext_vector_type(8)));
typedef short bf16x4 __attribute__((ext_vector_type(4)));

// f32 -> bf16 bits via HW convert (compiler pairs into v_cvt_pk_bf16_f32)
__device__ __forceinline__ short f2bf(float f) {
    return (short)__builtin_bit_cast(unsigned short, __float2bfloat16(f));
}
__device__ __forceinline__ float bf2f(short s) {
    unsigned u = ((unsigned)(unsigned short)s) << 16;
    return __builtin_bit_cast(float, u);
}

// ---------------------------------------------------------------------------
// Kernel 1: pack B operands, LDS-staged for full coalescing. (unchanged R7)
// Layout: B[j][h][c][i], j = d/32, h = (d/8)&3, i = d&7, c = column 0..15.
// ---------------------------------------------------------------------------
__global__ __launch_bounds__(256) void fm_pack(
        const float* __restrict__ w, const float* __restrict__ v,
        short* __restrict__ Bv, short* __restrict__ Bc) {
    __shared__ float vt[128][17];         // +1 pad: bank-spread columns
    __shared__ float wt[128];
    const int t  = threadIdx.x;
    const int jb = blockIdx.x * 4;
    const int d_base = jb * 32;
    const int nd = (DIM - d_base < 128) ? (DIM - d_base) : 128;

    #pragma unroll
    for (int q = 0; q < 2; ++q) {
        int e = t * 8 + q * 4;
        if (e < nd * 16) {
            f32x4 r = *(const f32x4*)(v + (size_t)d_base * 16 + e);
            #pragma unroll
            for (int i = 0; i < 4; ++i) vt[(e + i) >> 4][(e + i) & 15] = r[i];
        }
    }
    if (t < 32) {
        int d = t * 4;
        if (d < nd) {
            f32x4 r = *(const f32x4*)(w + d_base + d);
            #pragma unroll
            for (int i = 0; i < 4; ++i) if (d + i < nd) wt[d + i] = r[i];
        }
    }
    __syncthreads();

    const int jp = t >> 6;                // 0..3
    const int j  = jb + jp;
    if (j >= STEPS) return;
    const int rem = t & 63;
    const int h = rem >> 4, c = rem & 15;
    const int dl0 = jp * 32 + h * 8;
    size_t off = (size_t)j * 512 + h * 128 + c * 8;

    bf16x8 ov, oc;
    #pragma unroll
    for (int i = 0; i < 8; ++i) ov[i] = f2bf(vt[dl0 + i][c]);
    *(bf16x8*)(Bv + off) = ov;

    if (c == 0) {
        #pragma unroll
        for (int i = 0; i < 8; ++i) oc[i] = f2bf(wt[dl0 + i]);
    } else if (c == 1) {
        #pragma unroll
        for (int i = 0; i < 8; ++i) {
            float s = 0.f;
            #pragma unroll
            for (int k = 0; k < 16; ++k) { float vv = vt[dl0 + i][k]; s += vv * vv; }
            oc[i] = f2bf(s);
        }
    } else {
        oc = (bf16x8)0;
    }
    *(bf16x8*)(Bc + off) = oc;
}

// ---------------------------------------------------------------------------
// Kernel 2: main pass — barrier-free, wave-autonomous.
// Block = 1 wave, owns 16 rows x 1 split (~98 steps). Private 8KB LDS dbuf,
// tile = 16 rows x 128 cols (4 MFMA steps). ZERO __syncthreads: all ordering
// is intra-wave lgkmcnt/vmcnt. Grid 4096 = 128 rowtiles x 32 splits = exactly
// 16 blocks/CU (one generation). split = bid&31 -> split s pinned to XCD s%8
// (4 splits x ~200KB B per XCD L2).
// ---------------------------------------------------------------------------
__global__ __launch_bounds__(64, 4) void fm_main(
        const float* __restrict__ x,
        const short* __restrict__ Bv, const short* __restrict__ Bc,
        float* __restrict__ P) {
    const int bid     = blockIdx.x;
    const int split   = bid & 31;
    const int rowtile = bid >> 5;
    const int lane = threadIdx.x;
    const int c = lane & 15;              // MFMA A-row / B-col
    const int h = lane >> 4;              // k-group

    // splits 0..20: 98 steps (tail tile = 2); 21..31: 97 (tail = 1)
    const int step_base  = split * 97 + (split < 21 ? split : 21);
    const int tail_steps = (split < 21) ? 2 : 1;

    __shared__ short lds[2][16 * 128];    // bf16: 2 x 4KB, private to the wave

    const int col0s = step_base * 32;
    const int lrow2 = lane >> 5;          // which of the 2 rows per segment
    const int lcol  = (lane & 31) * 4;    // f32 col within 128-col row
    f32x4 st[8];                          // x staging: 8 segs x (2 rows/seg)
    bf16x8 bvr[4], bcr[4];                // B frags for this tile's 4 steps

    f32x4 acc_s = {0.f, 0.f, 0.f, 0.f};
    f32x4 acc_l = {0.f, 0.f, 0.f, 0.f};
    f32x4 acc_q = {0.f, 0.f, 0.f, 0.f};

    auto issue = [&](int t) {             // 8 loads, each = 2 rows x 512B
        if (t >= NTILES) return;
        const int ncols = (t < 24) ? 128 : tail_steps * 32;
        const bool ok = lcol < ncols;
        const int colf = col0s + t * 128 + lcol;
        #pragma unroll
        for (int L = 0; L < 8; ++L) {
            int r = L * 2 + lrow2;
            const float* p = x + (size_t)(rowtile * 16 + r) * DIM + colf;
            if (ok) st[L] = __builtin_nontemporal_load((const f32x4*)p);
        }
    };
    auto writeLDS = [&](int buf, int t) { // f32->bf16, XOR-swizzled 8B writes
        if (t >= NTILES) return;
        const int ncols = (t < 24) ? 128 : tail_steps * 32;
        const bool ok = lcol < ncols;
        char* base = (char*)&lds[buf][0];
        #pragma unroll
        for (int L = 0; L < 8; ++L) {
            int r = L * 2 + lrow2;
            int byte = r * 256 + ((lcol * 2) ^ ((r & 7) << 4));
            if (ok) {
                bf16x4 o;
                #pragma unroll
                for (int i = 0; i < 4; ++i) o[i] = f2bf(st[L][i]);
                *(bf16x4*)(base + byte) = o;
            }
        }
    };
    auto loadB = [&](int t) {
        if (t >= NTILES) return;
        int jbase = step_base + t * 4;
        #pragma unroll
        for (int ss = 0; ss < 4; ++ss) {
            int s = jbase + ss;
            if (s > STEPS - 1) s = STEPS - 1;   // tail clamp (unconsumed)
            size_t off = (size_t)s * 512 + h * 128 + c * 8;
            bvr[ss] = *(const bf16x8*)(Bv + off);
            bcr[ss] = *(const bf16x8*)(Bc + off);
        }
    };
    auto compute = [&](int buf, int t) {
        const int nsteps = (t < 24) ? 4 : tail_steps;
        const char* base = (const char*)&lds[buf][0];
        const int swz = (c & 7) << 4;
        #pragma unroll
        for (int ss = 0; ss < 4; ++ss) {
            if (ss < nsteps) {
                bf16x8 a1 = *(const bf16x8*)(base + (c * 256 + ((ss * 64 + h * 16) ^ swz)));
                bf16x8 a2;
                #pragma unroll
                for (int i = 0; i < 8; ++i) {
                    float f = bf2f(a1[i]);
                    a2[i] = f2bf(f * f);
                }
                acc_s = __builtin_amdgcn_mfma_f32_16x16x32_bf16(a1, bvr[ss], acc_s, 0, 0, 0);
                acc_l = __builtin_amdgcn_mfma_f32_16x16x32_bf16(a1, bcr[ss], acc_l, 0, 0, 0);
                acc_q = __builtin_amdgcn_mfma_f32_16x16x32_bf16(a2, bcr[ss], acc_q, 0, 0, 0);
            }
        }
    };

    // self-paced pipeline: no barriers anywhere
    issue(0);
    for (int t = 0; t < NTILES; ++t) {
        loadB(t);                 // L2-resident B: issued early, consumed last
        writeLDS(t & 1, t);       // waits own x(t) loads (issued a tile ago)
        issue(t + 1);             // next x tile in flight during compute
        compute(t & 1, t);        // lgkmcnt orders own ds_write -> ds_read
    }

    // epilogue: this wave owns its full k-range -> write P directly
    // C/D layout: col = lane&15, row = (lane>>4)*4 + reg  [verified m89]
    #pragma unroll
    for (int r = 0; r < 4; ++r) {
        size_t row = (size_t)rowtile * 16 + h * 4 + r;
        float* Pp = P + (row * NSPLIT + split) * 18;
        Pp[c] = acc_s[r];
        if (c == 0) Pp[16] = acc_l[r];
        if (c == 1) Pp[17] = acc_q[r];
    }
}

// ---------------------------------------------------------------------------
// Kernel 3: reduce partials. One wave per batch row; lane = split (<32).
// out[b] = lin + 0.5*(sum_k s_k^2 - ss)
// ---------------------------------------------------------------------------
__global__ __launch_bounds__(64) void fm_reduce(const float* __restrict__ P,
                                                float* __restrict__ out) {
    int b = blockIdx.x;
    int lane = threadIdx.x;               // 0..63; splits 0..31 active
    float r[18];
    if (lane < NSPLIT) {
        const float* q = P + ((size_t)b * NSPLIT + lane) * 18;
        #pragma unroll
        for (int i = 0; i < 18; ++i) r[i] = q[i];
    } else {
        #pragma unroll
        for (int i = 0; i < 18; ++i) r[i] = 0.f;
    }
    #pragma unroll
    for (int off = 16; off > 0; off >>= 1) {
        #pragma unroll
        for (int i = 0; i < 18; ++i) r[i] += __shfl_xor(r[i], off, 64);
    }
    if (lane == 0) {
        float acc = r[16] - 0.5f * r[17];
        #pragma unroll
        for (int k = 0; k < 16; ++k) acc += 0.5f * r[k] * r[k];
        out[b] = acc;
    }
}

// ---------------------------------------------------------------------------
extern "C" void kernel_launch(void* const* d_in, const int* in_sizes, int n_in,
                              void* d_out, int out_size, void* d_ws, size_t ws_size,
                              hipStream_t stream) {
    const float* x = (const float*)d_in[0];   // [2048, 100000]
    const float* w = (const float*)d_in[1];   // [100000, 1]
    const float* v = (const float*)d_in[2];   // [100000, 16]
    float* out = (float*)d_out;               // [2048]

    char* ws = (char*)d_ws;
    short* Bv = (short*)(ws);                 // 3.2 MB
    short* Bc = (short*)(ws + 3200000);       // 3.2 MB
    float* P  = (float*)(ws + 6400000);       // 2048*32*18*4 = 4.72 MB

    fm_pack<<<(STEPS + 3) / 4, 256, 0, stream>>>(w, v, Bv, Bc);
    fm_main<<<NSPLIT * ROWTILES, 64, 0, stream>>>(x, Bv, Bc, P);
    fm_reduce<<<BATCH, 64, 0, stream>>>(P, out);
}

// Round 9
// 158.420 us; speedup vs baseline: 1.1285x; 1.1285x over previous
//
#include <hip/hip_runtime.h>
#include <hip/hip_bf16.h>

#define BATCH 2048
#define DIM   100000
#define STEPS 3125              // DIM / 32 (exact)
#define NSPLIT 8                // 5 splits of 391 steps + 3 of 390 (=3125)
#define NTILES 25               // 24 full 16-step tiles + tail (7 or 6 steps)
#define ROWTILES 128            // 2048 / 16

typedef float f32x4  __attribute__((ext_vector_type(4)));
typedef short bf16x8 __attribute__((ext_vector_type(8)));
typedef short bf16x4 __attribute__((ext_vector_type(4)));

// f32 -> bf16 bits via HW convert (compiler pairs into v_cvt_pk_bf16_f32)
__device__ __forceinline__ short f2bf(float f) {
    return (short)__builtin_bit_cast(unsigned short, __float2bfloat16(f));
}
__device__ __forceinline__ float bf2f(short s) {
    unsigned u = ((unsigned)(unsigned short)s) << 16;
    return __builtin_bit_cast(float, u);
}

// ---------------------------------------------------------------------------
// Kernel 1: pack B operands, LDS-staged for full coalescing. (unchanged R7)
// Layout: B[j][h][c][i], j = d/32, h = (d/8)&3, i = d&7, c = column 0..15.
// ---------------------------------------------------------------------------
__global__ __launch_bounds__(256) void fm_pack(
        const float* __restrict__ w, const float* __restrict__ v,
        short* __restrict__ Bv, short* __restrict__ Bc) {
    __shared__ float vt[128][17];         // +1 pad: bank-spread columns
    __shared__ float wt[128];
    const int t  = threadIdx.x;
    const int jb = blockIdx.x * 4;
    const int d_base = jb * 32;
    const int nd = (DIM - d_base < 128) ? (DIM - d_base) : 128;

    #pragma unroll
    for (int q = 0; q < 2; ++q) {
        int e = t * 8 + q * 4;
        if (e < nd * 16) {
            f32x4 r = *(const f32x4*)(v + (size_t)d_base * 16 + e);
            #pragma unroll
            for (int i = 0; i < 4; ++i) vt[(e + i) >> 4][(e + i) & 15] = r[i];
        }
    }
    if (t < 32) {
        int d = t * 4;
        if (d < nd) {
            f32x4 r = *(const f32x4*)(w + d_base + d);
            #pragma unroll
            for (int i = 0; i < 4; ++i) if (d + i < nd) wt[d + i] = r[i];
        }
    }
    __syncthreads();

    const int jp = t >> 6;                // 0..3
    const int j  = jb + jp;
    if (j >= STEPS) return;
    const int rem = t & 63;
    const int h = rem >> 4, c = rem & 15;
    const int dl0 = jp * 32 + h * 8;
    size_t off = (size_t)j * 512 + h * 128 + c * 8;

    bf16x8 ov, oc;
    #pragma unroll
    for (int i = 0; i < 8; ++i) ov[i] = f2bf(vt[dl0 + i][c]);
    *(bf16x8*)(Bv + off) = ov;

    if (c == 0) {
        #pragma unroll
        for (int i = 0; i < 8; ++i) oc[i] = f2bf(wt[dl0 + i]);
    } else if (c == 1) {
        #pragma unroll
        for (int i = 0; i < 8; ++i) {
            float s = 0.f;
            #pragma unroll
            for (int k = 0; k < 16; ++k) { float vv = vt[dl0 + i][k]; s += vv * vv; }
            oc[i] = f2bf(s);
        }
    } else {
        oc = (bf16x8)0;
    }
    *(bf16x8*)(Bc + off) = oc;
}

// ---------------------------------------------------------------------------
// Kernel 2: main pass — R7 structure (best: 158.5) with ONE change: the
// per-tile __syncthreads() is replaced by {lgkmcnt(0); raw s_barrier}, so
// the x-loads of tile t+2 stay IN FLIGHT across the barrier instead of
// being drained by the compiler's vmcnt(0)-before-s_barrier. ds_writes are
// drained (lgkmcnt) for cross-wave visibility; vmem loads land in private
// registers -> no cross-wave hazard. writeLDS's wait on its own x-loads is
// the compiler's dep-based counted vmcnt, unchanged.
// ---------------------------------------------------------------------------
__global__ __launch_bounds__(256, 4) void fm_main(
        const float* __restrict__ x,
        const short* __restrict__ Bv, const short* __restrict__ Bc,
        float* __restrict__ P) {
    const int bid     = blockIdx.x;
    const int split   = bid & 7;
    const int rowtile = bid >> 3;
    const int lane = threadIdx.x & 63;
    const int wave = threadIdx.x >> 6;
    const int c = lane & 15;              // MFMA A-row / B-col
    const int h = lane >> 4;              // k-group

    const int step_base  = split * 390 + (split < 5 ? split : 5);
    const int tail_steps = 6 + (split < 5 ? 1 : 0);   // steps in tile 24

    __shared__ short lds[2][16 * 512];    // bf16 tile: 2 x 16KB

    const int col0s = step_base * 32;
    f32x4 st[4][2];                       // x staging: 4 rows x 8 f32
    bf16x8 bvr[4], bcr[4];                // B frags, 4 steps/wave (unroll-idx)

    f32x4 acc_s = {0.f, 0.f, 0.f, 0.f};
    f32x4 acc_l = {0.f, 0.f, 0.f, 0.f};
    f32x4 acc_q = {0.f, 0.f, 0.f, 0.f};

    auto issue = [&](int t) {             // 2 contiguous 1KB wave-segments/row
        if (t >= NTILES) return;
        const int ncols = (t < 24) ? 512 : tail_steps * 32;
        const int colf = col0s + t * 512;
        #pragma unroll
        for (int R = 0; R < 4; ++R) {
            int r = wave * 4 + R;
            const float* p = x + (size_t)(rowtile * 16 + r) * DIM + colf;
            if (lane * 4 < ncols)
                st[R][0] = __builtin_nontemporal_load((const f32x4*)(p + lane * 4));
            if (256 + lane * 4 < ncols)
                st[R][1] = __builtin_nontemporal_load((const f32x4*)(p + 256 + lane * 4));
        }
    };
    auto writeLDS = [&](int buf, int t) { // convert f32->bf16, swizzled b64 x2
        if (t >= NTILES) return;
        const int ncols = (t < 24) ? 512 : tail_steps * 32;
        #pragma unroll
        for (int R = 0; R < 4; ++R) {
            int r = wave * 4 + R;
            int swz = (r & 7) << 4;
            char* base = (char*)&lds[buf][0];
            if (lane * 4 < ncols) {
                bf16x4 o;
                #pragma unroll
                for (int i = 0; i < 4; ++i) o[i] = f2bf(st[R][0][i]);
                *(bf16x4*)(base + (r * 1024 + ((lane * 8) ^ swz))) = o;
            }
            if (256 + lane * 4 < ncols) {
                bf16x4 o;
                #pragma unroll
                for (int i = 0; i < 4; ++i) o[i] = f2bf(st[R][1][i]);
                *(bf16x4*)(base + (r * 1024 + ((512 + lane * 8) ^ swz))) = o;
            }
        }
    };
    auto loadB = [&](int t) {             // reload into same regs (1 tile ahead)
        if (t >= NTILES) return;
        int jbase = step_base + t * 16;
        #pragma unroll
        for (int ss = 0; ss < 4; ++ss) {
            int s = jbase + wave * 4 + ss;
            if (s > STEPS - 1) s = STEPS - 1;       // tail clamp (unconsumed)
            size_t off = (size_t)s * 512 + h * 128 + c * 8;
            bvr[ss] = *(const bf16x8*)(Bv + off);
            bcr[ss] = *(const bf16x8*)(Bc + off);
        }
    };
    auto compute = [&](int buf, int t) {
        const int nsteps = (t < 24) ? 16 : tail_steps;
        const char* base = (const char*)&lds[buf][0];
        const int swz = (c & 7) << 4;
        #pragma unroll
        for (int ss = 0; ss < 4; ++ss) {
            int s = wave * 4 + ss;
            if (s < nsteps) {
                bf16x8 a1 = *(const bf16x8*)(base + (c * 1024 + ((s * 64 + h * 16) ^ swz)));
                bf16x8 a2;
                #pragma unroll
                for (int i = 0; i < 8; ++i) {
                    float f = bf2f(a1[i]);
                    a2[i] = f2bf(f * f);
                }
                acc_s = __builtin_amdgcn_mfma_f32_16x16x32_bf16(a1, bvr[ss], acc_s, 0, 0, 0);
                acc_l = __builtin_amdgcn_mfma_f32_16x16x32_bf16(a1, bcr[ss], acc_l, 0, 0, 0);
                acc_q = __builtin_amdgcn_mfma_f32_16x16x32_bf16(a2, bcr[ss], acc_q, 0, 0, 0);
            }
        }
    };
    // barrier that does NOT drain vmcnt: ds_writes made visible (lgkmcnt 0),
    // in-flight global loads (private regs) carry across. Rule #18 fences.
    auto barrier_keep_inflight = [&]() {
        __builtin_amdgcn_sched_barrier(0);
        asm volatile("s_waitcnt lgkmcnt(0)" ::: "memory");
        __builtin_amdgcn_s_barrier();
        __builtin_amdgcn_sched_barrier(0);
    };

    // prologue
    loadB(0);
    issue(0);
    writeLDS(0, 0);                       // dep-based wait on tile-0 loads
    issue(1);
    // steady state: 1 barrier per tile, vmcnt never drained to 0
    for (int t = 0; t < NTILES; ++t) {
        barrier_keep_inflight();
        compute(t & 1, t);                // consumes B loaded a tile ago
        loadB(t + 1);                     // refill B regs (L2-resident)
        writeLDS((t + 1) & 1, t + 1);     // counted vmcnt: waits x(t+1) only
        issue(t + 2);                     // stays in flight across barrier
    }

    // epilogue: cross-wave k-partial reduction (full __syncthreads is fine)
    __syncthreads();
    float* red = (float*)&lds[0][0];      // 256 threads x 12 floats = 12KB
    int rbase = (wave * 64 + lane) * 12;
    #pragma unroll
    for (int i = 0; i < 4; ++i) {
        red[rbase + i]     = acc_s[i];
        red[rbase + 4 + i] = acc_l[i];
        red[rbase + 8 + i] = acc_q[i];
    }
    __syncthreads();
    if (wave == 0) {
        f32x4 s = {0,0,0,0}, l = {0,0,0,0}, q = {0,0,0,0};
        #pragma unroll
        for (int wv = 0; wv < 4; ++wv) {
            const float* rp = &red[(wv * 64 + lane) * 12];
            #pragma unroll
            for (int i = 0; i < 4; ++i) {
                s[i] += rp[i]; l[i] += rp[4 + i]; q[i] += rp[8 + i];
            }
        }
        // C/D layout: col = lane&15, row = (lane>>4)*4 + reg  [verified m89]
        #pragma unroll
        for (int r = 0; r < 4; ++r) {
            size_t row = (size_t)rowtile * 16 + h * 4 + r;
            float* Pp = P + (row * NSPLIT + split) * 18;
            Pp[c] = s[r];
            if (c == 0) Pp[16] = l[r];
            if (c == 1) Pp[17] = q[r];
        }
    }
}

// ---------------------------------------------------------------------------
// Kernel 3: reduce partials. One wave per batch row; lane = split (<8).
// out[b] = lin + 0.5*(sum_k s_k^2 - ss)                       (unchanged R7)
// ---------------------------------------------------------------------------
__global__ __launch_bounds__(64) void fm_reduce(const float* __restrict__ P,
                                                float* __restrict__ out) {
    int b = blockIdx.x;
    int lane = threadIdx.x;               // 0..63; splits 0..7 active
    float r[18];
    if (lane < NSPLIT) {
        const float* q = P + ((size_t)b * NSPLIT + lane) * 18;
        #pragma unroll
        for (int i = 0; i < 18; ++i) r[i] = q[i];
    } else {
        #pragma unroll
        for (int i = 0; i < 18; ++i) r[i] = 0.f;
    }
    #pragma unroll
    for (int off = 4; off > 0; off >>= 1) {
        #pragma unroll
        for (int i = 0; i < 18; ++i) r[i] += __shfl_xor(r[i], off, 64);
    }
    if (lane == 0) {
        float acc = r[16] - 0.5f * r[17];
        #pragma unroll
        for (int k = 0; k < 16; ++k) acc += 0.5f * r[k] * r[k];
        out[b] = acc;
    }
}

// ---------------------------------------------------------------------------
extern "C" void kernel_launch(void* const* d_in, const int* in_sizes, int n_in,
                              void* d_out, int out_size, void* d_ws, size_t ws_size,
                              hipStream_t stream) {
    const float* x = (const float*)d_in[0];   // [2048, 100000]
    const float* w = (const float*)d_in[1];   // [100000, 1]
    const float* v = (const float*)d_in[2];   // [100000, 16]
    float* out = (float*)d_out;               // [2048]

    char* ws = (char*)d_ws;
    short* Bv = (short*)(ws);                 // 3.2 MB
    short* Bc = (short*)(ws + 3200000);       // 3.2 MB
    float* P  = (float*)(ws + 6400000);       // 2048*8*18*4 = 1.18 MB

    fm_pack<<<(STEPS + 3) / 4, 256, 0, stream>>>(w, v, Bv, Bc);
    fm_main<<<NSPLIT * ROWTILES, 256, 0, stream>>>(x, Bv, Bc, P);
    fm_reduce<<<BATCH, 64, 0, stream>>>(P, out);
}